// Round 3
// baseline (29.879 us; speedup 1.0000x reference)
//
#include <hip/hip_runtime.h>

#define BATCH   16384
#define NF      1024
#define NWAVES  2048
#define NPAIRS  (BATCH / 2 / NWAVES)   // 4 row-pairs per wave

// One wave per PAIR of adjacent batch rows; 4 pairs per wave.
// Lane l owns columns {4*l + 256*k + j : k in 0..3, j in 0..3}.
// W rows 0..9 per-lane slices live in registers (shared across all rows).
// Leaf slice lives in LDS (read once per pair).
// Next pair's x (8 KB/wave) is prefetched while current pair computes.
__global__ __launch_bounds__(256, 2)
void sdt_kernel(const float* __restrict__ x,
                const float* __restrict__ W,
                const float* __restrict__ b,
                const float* __restrict__ leaf,
                float* __restrict__ out)
{
    const int lane = threadIdx.x & 63;
    const int wid  = (int)((blockIdx.x * blockDim.x + threadIdx.x) >> 6);

    __shared__ float lv_s[1024];
    // stage leaf values: 256 threads x float4
    *reinterpret_cast<float4*>(&lv_s[threadIdx.x * 4]) =
        *reinterpret_cast<const float4*>(leaf + threadIdx.x * 4);

    // ---- preload W slices: Wr[d][k] = W[d][256k + 4l .. +3] ----
    float4 Wr[10][4];
#pragma unroll
    for (int d = 0; d < 10; ++d)
#pragma unroll
        for (int k = 0; k < 4; ++k)
            Wr[d][k] = *reinterpret_cast<const float4*>(W + d * NF + k * 256 + 4 * lane);

    float bias[10];
#pragma unroll
    for (int d = 0; d < 10; ++d) bias[d] = b[d];

    __syncthreads();

    // ---- prologue: load first pair (rows 2*wid, 2*wid+1) ----
    float4 xv[2][4];
    {
        const float* xr = x + (size_t)(2 * wid) * NF;
#pragma unroll
        for (int r = 0; r < 2; ++r)
#pragma unroll
            for (int k = 0; k < 4; ++k)
                xv[r][k] = *reinterpret_cast<const float4*>(xr + r * NF + k * 256 + 4 * lane);
    }

    for (int i = 0; i < NPAIRS; ++i) {
        const int rowA = 2 * (wid + i * NWAVES);

        // ---- prefetch next pair ----
        float4 xn[2][4];
        if (i + 1 < NPAIRS) {
            const float* xr = x + (size_t)(rowA + 2 * NWAVES) * NF;
#pragma unroll
            for (int r = 0; r < 2; ++r)
#pragma unroll
                for (int k = 0; k < 4; ++k)
                    xn[r][k] = *reinterpret_cast<const float4*>(xr + r * NF + k * 256 + 4 * lane);
        }

        // ---- row A: partial dots, then reduce (B's FMAs overlap A's shuffles) ----
        float accA[10];
#pragma unroll
        for (int d = 0; d < 10; ++d) {
            float a = 0.0f;
#pragma unroll
            for (int k = 0; k < 4; ++k) {
                a = fmaf(xv[0][k].x, Wr[d][k].x, a);
                a = fmaf(xv[0][k].y, Wr[d][k].y, a);
                a = fmaf(xv[0][k].z, Wr[d][k].z, a);
                a = fmaf(xv[0][k].w, Wr[d][k].w, a);
            }
            accA[d] = a;
        }
#pragma unroll
        for (int d = 0; d < 10; ++d) {
            float a = accA[d];
#pragma unroll
            for (int off = 32; off > 0; off >>= 1)
                a += __shfl_xor(a, off, 64);
            accA[d] = a;
        }

        // ---- row B ----
        float accB[10];
#pragma unroll
        for (int d = 0; d < 10; ++d) {
            float a = 0.0f;
#pragma unroll
            for (int k = 0; k < 4; ++k) {
                a = fmaf(xv[1][k].x, Wr[d][k].x, a);
                a = fmaf(xv[1][k].y, Wr[d][k].y, a);
                a = fmaf(xv[1][k].z, Wr[d][k].z, a);
                a = fmaf(xv[1][k].w, Wr[d][k].w, a);
            }
            accB[d] = a;
        }
#pragma unroll
        for (int d = 0; d < 10; ++d) {
            float a = accB[d];
#pragma unroll
            for (int off = 32; off > 0; off >>= 1)
                a += __shfl_xor(a, off, 64);
            accB[d] = a;
        }

        // ---- gates for both rows (fast rcp; ~1 ulp, threshold 2.4e-5) ----
        float g[2][10];
#pragma unroll
        for (int d = 0; d < 10; ++d) {
            g[0][d] = __builtin_amdgcn_rcpf(1.0f + __expf(-(accA[d] + bias[d])));
            g[1][d] = __builtin_amdgcn_rcpf(1.0f + __expf(-(accB[d] + bias[d])));
        }

        // ---- leaf slice from LDS (shared by both rows) ----
        float Lv[16];
#pragma unroll
        for (int k = 0; k < 4; ++k) {
            float4 t = *reinterpret_cast<const float4*>(&lv_s[16 * lane + 4 * k]);
            Lv[4 * k + 0] = t.x; Lv[4 * k + 1] = t.y;
            Lv[4 * k + 2] = t.z; Lv[4 * k + 3] = t.w;
        }

        // ---- DP + path weight + weighted wave-sum, per row ----
        float vout[2];
#pragma unroll
        for (int r = 0; r < 2; ++r) {
            float s9[8];
#pragma unroll
            for (int j = 0; j < 8; ++j)
                s9[j] = fmaf(g[r][9], Lv[2 * j + 1] - Lv[2 * j], Lv[2 * j]);
            float s8[4];
#pragma unroll
            for (int j = 0; j < 4; ++j)
                s8[j] = fmaf(g[r][8], s9[2 * j + 1] - s9[2 * j], s9[2 * j]);
            float s7[2];
#pragma unroll
            for (int j = 0; j < 2; ++j)
                s7[j] = fmaf(g[r][7], s8[2 * j + 1] - s8[2 * j], s8[2 * j]);
            float s6 = fmaf(g[r][6], s7[1] - s7[0], s7[0]);

            // lane index = tree bits d=0..5, d=0 is MSB
            float w = 1.0f;
#pragma unroll
            for (int d = 0; d < 6; ++d) {
                int bit = (lane >> (5 - d)) & 1;
                w *= bit ? g[r][d] : (1.0f - g[r][d]);
            }

            float v = w * s6;
#pragma unroll
            for (int off = 32; off > 0; off >>= 1)
                v += __shfl_xor(v, off, 64);
            vout[r] = v;
        }

        if (lane == 0) {
            out[rowA]     = vout[0];
            out[rowA + 1] = vout[1];
        }

        // ---- rotate pipeline ----
#pragma unroll
        for (int r = 0; r < 2; ++r)
#pragma unroll
            for (int k = 0; k < 4; ++k)
                xv[r][k] = xn[r][k];
    }
}

extern "C" void kernel_launch(void* const* d_in, const int* in_sizes, int n_in,
                              void* d_out, int out_size, void* d_ws, size_t ws_size,
                              hipStream_t stream) {
    const float* x    = (const float*)d_in[0];
    const float* W    = (const float*)d_in[1];
    const float* b    = (const float*)d_in[2];
    const float* leaf = (const float*)d_in[3];
    float* out = (float*)d_out;

    const int blocks  = 512;   // 2048 waves = 2 waves/SIMD across 256 CUs
    const int threads = 256;

    sdt_kernel<<<blocks, threads, 0, stream>>>(x, W, b, leaf, out);
}

// Round 5
// 26.118 us; speedup vs baseline: 1.1440x; 1.1440x over previous
//
#include <hip/hip_runtime.h>

#define BATCH   16384
#define NF      1024
#define NWAVES  2048

// One wave per batch row, 8 rows per wave, next-row x prefetched.
// Lane l owns columns {4*l + 256*k + j : k in 0..3, j in 0..3}.
// W rows 0..9 per-lane slices live in registers (shared across all rows).
// Reductions: DPP quad_perm/row_ror (full permutations only — direction- and
// boundary-safe) + v_readlane cross-row. Zero LDS-pipe ops.

template <int CTRL>
__device__ __forceinline__ float dpp_add(float x) {
    int xi = __builtin_bit_cast(int, x);
    // full permutation, all masks on, bound_ctrl false (no invalid lanes)
    int yi = __builtin_amdgcn_update_dpp(xi, xi, CTRL, 0xf, 0xf, false);
    return x + __builtin_bit_cast(float, yi);
}

// After this, EVERY lane holds the sum of its 16-lane row.
__device__ __forceinline__ float row_reduce_dpp(float x) {
    x = dpp_add<0xB1>(x);    // quad_perm [1,0,3,2]: neighbor swap
    x = dpp_add<0x4E>(x);    // quad_perm [2,3,0,1]: pair swap -> quad sums
    x = dpp_add<0x124>(x);   // row_ror:4 -> sum of 2 quads
    x = dpp_add<0x128>(x);   // row_ror:8 -> row sum (direction-independent)
    return x;
}

// Wave-uniform total via readlane of the 4 row sums (pure VALU).
__device__ __forceinline__ float wave_sum(float x) {
    float r = row_reduce_dpp(x);
    int ri = __builtin_bit_cast(int, r);
    float s0 = __builtin_bit_cast(float, __builtin_amdgcn_readlane(ri, 0));
    float s1 = __builtin_bit_cast(float, __builtin_amdgcn_readlane(ri, 16));
    float s2 = __builtin_bit_cast(float, __builtin_amdgcn_readlane(ri, 32));
    float s3 = __builtin_bit_cast(float, __builtin_amdgcn_readlane(ri, 48));
    return (s0 + s1) + (s2 + s3);
}

__global__ __launch_bounds__(256, 2)
void sdt_kernel(const float* __restrict__ x,
                const float* __restrict__ W,
                const float* __restrict__ b,
                const float* __restrict__ leaf,
                float* __restrict__ out)
{
    const int lane = threadIdx.x & 63;
    const int wid  = (int)((blockIdx.x * blockDim.x + threadIdx.x) >> 6);

    // ---- preload W slices: Wr[d][k] = W[d][256k + 4l .. +3] ----
    float4 Wr[10][4];
#pragma unroll
    for (int d = 0; d < 10; ++d)
#pragma unroll
        for (int k = 0; k < 4; ++k)
            Wr[d][k] = *reinterpret_cast<const float4*>(W + d * NF + k * 256 + 4 * lane);

    // bias: uniform -> scalar loads
    float bias[10];
#pragma unroll
    for (int d = 0; d < 10; ++d) bias[d] = b[d];

    // ---- preload leaf slice: Lv[i] = leaf[16*lane + i] ----
    float Lv[16];
#pragma unroll
    for (int k = 0; k < 4; ++k) {
        float4 t = *reinterpret_cast<const float4*>(leaf + 16 * lane + 4 * k);
        Lv[4 * k + 0] = t.x; Lv[4 * k + 1] = t.y;
        Lv[4 * k + 2] = t.z; Lv[4 * k + 3] = t.w;
    }

    // ---- prologue: load first row ----
    float4 xv[4];
    {
        const float* xr = x + (size_t)wid * NF;
#pragma unroll
        for (int k = 0; k < 4; ++k)
            xv[k] = *reinterpret_cast<const float4*>(xr + k * 256 + 4 * lane);
    }

    for (int row = wid; row < BATCH; row += NWAVES) {
        // ---- prefetch next row (waited at rotate, after compute) ----
        float4 xn[4];
        const int nrow = row + NWAVES;
        if (nrow < BATCH) {
            const float* xr = x + (size_t)nrow * NF;
#pragma unroll
            for (int k = 0; k < 4; ++k)
                xn[k] = *reinterpret_cast<const float4*>(xr + k * 256 + 4 * lane);
        }

        // ---- 10 partial dots (independent FMA chains) ----
        float acc[10];
#pragma unroll
        for (int d = 0; d < 10; ++d) {
            float a = 0.0f;
#pragma unroll
            for (int k = 0; k < 4; ++k) {
                a = fmaf(xv[k].x, Wr[d][k].x, a);
                a = fmaf(xv[k].y, Wr[d][k].y, a);
                a = fmaf(xv[k].z, Wr[d][k].z, a);
                a = fmaf(xv[k].w, Wr[d][k].w, a);
            }
            acc[d] = a;
        }

        // ---- gates: wave-uniform z via DPP+readlane reduce (pure VALU) ----
        // g = 1/(1+e^-z), 1-g = e^-z * g
        float g[10], gc[10];
#pragma unroll
        for (int d = 0; d < 10; ++d) {
            float z = wave_sum(acc[d]) + bias[d];
            float e = __expf(-z);
            g[d]  = __builtin_amdgcn_rcpf(1.0f + e);
            gc[d] = e * g[d];
        }

        // ---- DP over leaves: contract leaf LSB (depth 9) upward ----
        float s9[8];
#pragma unroll
        for (int j = 0; j < 8; ++j)
            s9[j] = fmaf(g[9], Lv[2 * j + 1] - Lv[2 * j], Lv[2 * j]);
        float s8[4];
#pragma unroll
        for (int j = 0; j < 4; ++j)
            s8[j] = fmaf(g[8], s9[2 * j + 1] - s9[2 * j], s9[2 * j]);
        float s7[2];
#pragma unroll
        for (int j = 0; j < 2; ++j)
            s7[j] = fmaf(g[7], s8[2 * j + 1] - s8[2 * j], s8[2 * j]);
        float s6 = fmaf(g[6], s7[1] - s7[0], s7[0]);

        // ---- per-lane 6-bit path weight: lane index = bits d=0..5, d=0 MSB ----
        float w = 1.0f;
#pragma unroll
        for (int d = 0; d < 6; ++d) {
            int bit = (lane >> (5 - d)) & 1;
            w *= bit ? g[d] : gc[d];
        }

        // ---- weighted wave-sum (DPP+readlane); lane 0 stores ----
        float v = wave_sum(w * s6);
        if (lane == 0) out[row] = v;

        // ---- rotate pipeline ----
#pragma unroll
        for (int k = 0; k < 4; ++k) xv[k] = xn[k];
    }
}

extern "C" void kernel_launch(void* const* d_in, const int* in_sizes, int n_in,
                              void* d_out, int out_size, void* d_ws, size_t ws_size,
                              hipStream_t stream) {
    const float* x    = (const float*)d_in[0];
    const float* W    = (const float*)d_in[1];
    const float* b    = (const float*)d_in[2];
    const float* leaf = (const float*)d_in[3];
    float* out = (float*)d_out;

    const int blocks  = 512;   // 2048 waves = 2 waves/SIMD across 256 CUs
    const int threads = 256;

    sdt_kernel<<<blocks, threads, 0, stream>>>(x, W, b, leaf, out);
}

// Round 6
// 25.268 us; speedup vs baseline: 1.1825x; 1.0336x over previous
//
#include <hip/hip_runtime.h>

#define BATCH   16384
#define NF      1024
#define NWAVES  2048
#define NITER   (BATCH / NWAVES)   // 8 rows per wave

// One wave per batch row, 8 rows per wave, x prefetched TWO rows ahead
// (3 rolling register buffers, statically indexed -> no scratch).
// Lane l owns columns {4*l + 256*k + j : k in 0..3, j in 0..3}.
// W rows 0..9 per-lane slices live in registers (shared across all rows).
// Leaf values live in LDS, transposed (lv_t[i*64+lane]) -> conflict-free reads.
// Reductions: DPP quad_perm/row_ror (full permutations) + readlane. Pure VALU.

template <int CTRL>
__device__ __forceinline__ float dpp_add(float x) {
    int xi = __builtin_bit_cast(int, x);
    int yi = __builtin_amdgcn_update_dpp(xi, xi, CTRL, 0xf, 0xf, false);
    return x + __builtin_bit_cast(float, yi);
}

__device__ __forceinline__ float row_reduce_dpp(float x) {
    x = dpp_add<0xB1>(x);    // quad_perm [1,0,3,2]
    x = dpp_add<0x4E>(x);    // quad_perm [2,3,0,1] -> quad sums
    x = dpp_add<0x124>(x);   // row_ror:4
    x = dpp_add<0x128>(x);   // row_ror:8 -> 16-lane row sum in every lane
    return x;
}

__device__ __forceinline__ float wave_sum(float x) {
    float r = row_reduce_dpp(x);
    int ri = __builtin_bit_cast(int, r);
    float s0 = __builtin_bit_cast(float, __builtin_amdgcn_readlane(ri, 0));
    float s1 = __builtin_bit_cast(float, __builtin_amdgcn_readlane(ri, 16));
    float s2 = __builtin_bit_cast(float, __builtin_amdgcn_readlane(ri, 32));
    float s3 = __builtin_bit_cast(float, __builtin_amdgcn_readlane(ri, 48));
    return (s0 + s1) + (s2 + s3);
}

__global__ __launch_bounds__(256, 2)
void sdt_kernel(const float* __restrict__ x,
                const float* __restrict__ W,
                const float* __restrict__ b,
                const float* __restrict__ leaf,
                float* __restrict__ out)
{
    const int lane = threadIdx.x & 63;
    const int wid  = (int)((blockIdx.x * blockDim.x + threadIdx.x) >> 6);

    // ---- leaf table, transposed: lv_t[i*64 + l] = leaf[l*16 + i] ----
    __shared__ float lv_t[1024];
    {
        const int t = threadIdx.x * 4;
#pragma unroll
        for (int e = 0; e < 4; ++e) {
            int idx = t + e;
            lv_t[idx] = leaf[(idx & 63) * 16 + (idx >> 6)];
        }
    }

    // ---- preload W slices: Wr[d][k] = W[d][256k + 4l .. +3] ----
    float4 Wr[10][4];
#pragma unroll
    for (int d = 0; d < 10; ++d)
#pragma unroll
        for (int k = 0; k < 4; ++k)
            Wr[d][k] = *reinterpret_cast<const float4*>(W + d * NF + k * 256 + 4 * lane);

    float bias[10];
#pragma unroll
    for (int d = 0; d < 10; ++d) bias[d] = b[d];

    __syncthreads();

    auto load_row = [&](float4 (&dst)[4], int r) {
        const float* xr = x + (size_t)r * NF;
#pragma unroll
        for (int k = 0; k < 4; ++k)
            dst[k] = *reinterpret_cast<const float4*>(xr + k * 256 + 4 * lane);
    };

    auto process_row = [&](const float4 (&xv)[4], int row) {
        // 10 partial dots
        float acc[10];
#pragma unroll
        for (int d = 0; d < 10; ++d) {
            float a = 0.0f;
#pragma unroll
            for (int k = 0; k < 4; ++k) {
                a = fmaf(xv[k].x, Wr[d][k].x, a);
                a = fmaf(xv[k].y, Wr[d][k].y, a);
                a = fmaf(xv[k].z, Wr[d][k].z, a);
                a = fmaf(xv[k].w, Wr[d][k].w, a);
            }
            acc[d] = a;
        }
        // gates (wave-uniform after DPP reduce)
        float g[10];
#pragma unroll
        for (int d = 0; d < 10; ++d) {
            float z = wave_sum(acc[d]) + bias[d];
            g[d] = __builtin_amdgcn_rcpf(1.0f + __expf(-z));
        }
        // leaf DP: contract LSB (depth 9) upward; leaves from LDS
        float s9[8];
#pragma unroll
        for (int j = 0; j < 8; ++j) {
            float La = lv_t[(2 * j) * 64 + lane];
            float Lb = lv_t[(2 * j + 1) * 64 + lane];
            s9[j] = fmaf(g[9], Lb - La, La);
        }
        float s8[4];
#pragma unroll
        for (int j = 0; j < 4; ++j)
            s8[j] = fmaf(g[8], s9[2 * j + 1] - s9[2 * j], s9[2 * j]);
        float s7[2];
#pragma unroll
        for (int j = 0; j < 2; ++j)
            s7[j] = fmaf(g[7], s8[2 * j + 1] - s8[2 * j], s8[2 * j]);
        float s6 = fmaf(g[6], s7[1] - s7[0], s7[0]);

        // per-lane 6-bit path weight (lane bits d=0..5, d=0 MSB)
        float w = 1.0f;
#pragma unroll
        for (int d = 0; d < 6; ++d) {
            int bit = (lane >> (5 - d)) & 1;
            w *= bit ? g[d] : (1.0f - g[d]);
        }

        float v = wave_sum(w * s6);
        if (lane == 0) out[row] = v;
    };

    // ---- 3-stage rolling pipeline: prefetch 2 rows ahead ----
    float4 xb0[4], xb1[4], xb2[4];
    load_row(xb0, wid);
    load_row(xb1, wid + 1 * NWAVES);

    load_row(xb2, wid + 2 * NWAVES); process_row(xb0, wid);
    load_row(xb0, wid + 3 * NWAVES); process_row(xb1, wid + 1 * NWAVES);
    load_row(xb1, wid + 4 * NWAVES); process_row(xb2, wid + 2 * NWAVES);
    load_row(xb2, wid + 5 * NWAVES); process_row(xb0, wid + 3 * NWAVES);
    load_row(xb0, wid + 6 * NWAVES); process_row(xb1, wid + 4 * NWAVES);
    load_row(xb1, wid + 7 * NWAVES); process_row(xb2, wid + 5 * NWAVES);
    process_row(xb0, wid + 6 * NWAVES);
    process_row(xb1, wid + 7 * NWAVES);
}

extern "C" void kernel_launch(void* const* d_in, const int* in_sizes, int n_in,
                              void* d_out, int out_size, void* d_ws, size_t ws_size,
                              hipStream_t stream) {
    const float* x    = (const float*)d_in[0];
    const float* W    = (const float*)d_in[1];
    const float* b    = (const float*)d_in[2];
    const float* leaf = (const float*)d_in[3];
    float* out = (float*)d_out;

    const int blocks  = 512;   // 2048 waves = 2 waves/SIMD across 256 CUs
    const int threads = 256;

    sdt_kernel<<<blocks, threads, 0, stream>>>(x, W, b, leaf, out);
}